// Round 9
// baseline (130.558 us; speedup 1.0000x reference)
//
#include <hip/hip_runtime.h>

typedef __bf16 bf16x8 __attribute__((ext_vector_type(8)));
typedef float  f32x4  __attribute__((ext_vector_type(4)));
typedef float  f32x16 __attribute__((ext_vector_type(16)));

#define HD     512            // H*D
#define NITEMS 1024           // 8 tt-levels x 128 (b,h) groups
#define C1     8.6316745750310966e-05f  // ALPHA/1024
#define C2     0.12751793f              // ALPHA*log2(e)

static __device__ __forceinline__ unsigned int cvt_pk_bf16(float lo, float hi) {
    unsigned int r;
    asm("v_cvt_pk_bf16_f32 %0, %1, %2" : "=v"(r) : "v"(lo), "v"(hi));
    return r;
}

union PA8 { unsigned int u[4]; bf16x8 v; };

// Persistent 4-wave blocks, dynamic LPT queue over 128-row tile items
// (tt-major, biggest first). Wave owns 32 q-rows = one 32x32 MFMA q-tile.
// KV chunk 32, ping-pong LDS (2 x 16KB), reg-prefetch 2 ahead.
// Barriers are lgkmcnt-only (global prefetch loads stay in flight across
// them — they feed private regs, no cross-wave visibility needed).
// QK^T swapped (S^T = mfma32(K,Q)); P redistributed to PV A-frags fully
// in-register via v_cvt_pk_bf16_f32 + v_permlane32_swap_b32 (no LDS, no bperm).
__global__ __launch_bounds__(256)
void hstu_attn_fwd(const float* __restrict__ Q, const float* __restrict__ K,
                   const float* __restrict__ V,
                   const int* __restrict__ offs,
                   const int* __restrict__ ntgt,
                   float* __restrict__ Out,
                   unsigned int* __restrict__ ctr)
{
    __shared__ __align__(16) char smem[32768];
    __shared__ int s_item;

    const int tid  = threadIdx.x;
    const int w    = tid >> 6;
    const int lane = tid & 63;
    const int l31  = lane & 31, h5 = lane >> 5;

    // staging decode
    const int kj0 = tid >> 4, kd8 = tid & 15;   // K: rows kj0, kj0+16; 16B unit kd8
    const int vg0 = tid >> 7, vd  = tid & 127;  // V: groups vg0, vg0+2; column vd

    for (;;) {
        __syncthreads();
        if (tid == 0) s_item = (int)atomicAdd(ctr, 1u);
        __syncthreads();
        const int it = s_item;
        if (it >= NITEMS) break;

        const int tt = it >> 7;            // 0..7, big tiles first
        const int G  = it & 127;
        const int b  = G >> 2, h = G & 3;

        const int s0 = offs[b];
        const int L  = offs[b + 1] - s0;
        const int T  = (L + 127) >> 7;     // 128-row tiles
        const int t  = T - 1 - tt;
        if (t < 0) continue;
        const int cap = L - ntgt[b];

        const float* Kb = K + (size_t)s0 * HD + h * 128;
        const float* Vb = V + (size_t)s0 * HD + h * 128;

        const int r0   = t << 7;
        const int wr0  = r0 + (w << 5);    // wave owns rows wr0..wr0+31
        const int qrow = wr0 + l31;        // this lane's q-row

        int wave_jmax;
        if (wr0 >= L)            wave_jmax = 0;
        else if (wr0 + 32 > cap) wave_jmax = L;
        else                     wave_jmax = wr0 + 32;

        const int jmax = (r0 + 128 > cap) ? L : (r0 + 128);
        const int nch  = (jmax + 31) >> 5;

        // ---- Q B-frags: lane reads Q[qrow][ks*16 + 8*h5 + e], e=0..7 ----
        bf16x8 qa[8];
        {
            int qr = qrow; if (qr > L - 1) qr = L - 1;
            const float* qp = Q + (size_t)(s0 + qr) * HD + h * 128 + h5 * 8;
#pragma unroll
            for (int ks = 0; ks < 8; ++ks) {
                f32x4 x0 = *(const f32x4*)(qp + ks * 16);
                f32x4 x1 = *(const f32x4*)(qp + ks * 16 + 4);
                bf16x8 a;
#pragma unroll
                for (int e = 0; e < 4; ++e) { a[e] = (__bf16)x0[e]; a[e + 4] = (__bf16)x1[e]; }
                qa[ks] = a;
            }
        }

        f32x16 oacc[4];
#pragma unroll
        for (int d = 0; d < 4; ++d)
#pragma unroll
            for (int r = 0; r < 16; ++r) oacc[d][r] = 0.f;

        f32x4 kreg[2][2];
        float vreg[16];

        auto load_chunk = [&](int j0c) {
#pragma unroll
            for (int s = 0; s < 2; ++s) {
                int j = j0c + kj0 + s * 16; if (j > L - 1) j = L - 1;
                const float* p = Kb + (size_t)j * HD + kd8 * 8;
                kreg[s][0] = *(const f32x4*)p;
                kreg[s][1] = *(const f32x4*)(p + 4);
            }
#pragma unroll
            for (int s = 0; s < 2; ++s) {
                const int gg = vg0 + s * 2;
#pragma unroll
                for (int e = 0; e < 8; ++e) {
                    int j = j0c + gg * 8 + e; if (j > L - 1) j = L - 1;
                    vreg[s * 8 + e] = Vb[(size_t)j * HD + vd];
                }
            }
        };
        auto write_buf = [&](int p) {
            char* wK = smem + p * 16384;
            char* wV = wK + 8192;
#pragma unroll
            for (int s = 0; s < 2; ++s) {
                const int j = kj0 + s * 16;
                bf16x8 kb;
#pragma unroll
                for (int e = 0; e < 4; ++e) { kb[e] = (__bf16)kreg[s][0][e]; kb[e + 4] = (__bf16)kreg[s][1][e]; }
                *(bf16x8*)(wK + ((j * 256 + kd8 * 16) ^ ((j & 7) << 4))) = kb;
            }
#pragma unroll
            for (int s = 0; s < 2; ++s) {
                bf16x8 vbw;
#pragma unroll
                for (int e = 0; e < 8; ++e) vbw[e] = (__bf16)vreg[s * 8 + e];
                *(bf16x8*)(wV + (vg0 + s * 2) * 2048 + vd * 16) = vbw;
            }
        };

        // prologue: chunk0 -> buf0; prefetch chunk1
        load_chunk(0);
        write_buf(0);
        if (nch > 1) load_chunk(32);
        asm volatile("s_waitcnt lgkmcnt(0)\n\ts_barrier" ::: "memory");

        for (int c = 0; c < nch; ++c) {
            const int j0 = c << 5;
            const char* bK = smem + (c & 1) * 16384;
            const char* bV = bK + 8192;

            if (j0 < wave_jmax) {
                // ---- S^T (32 j x 32 q) = mfma32(K, Q) over 8 k-steps ----
                f32x16 sacc;
#pragma unroll
                for (int r = 0; r < 16; ++r) sacc[r] = 0.f;
                __builtin_amdgcn_s_setprio(1);
#pragma unroll
                for (int ks = 0; ks < 8; ++ks) {
                    bf16x8 kb = *(const bf16x8*)(bK +
                        ((l31 * 256 + ks * 32 + h5 * 16) ^ ((l31 & 7) << 4)));
                    sacc = __builtin_amdgcn_mfma_f32_32x32x16_bf16(kb, qa[ks], sacc, 0, 0, 0);
                }
                __builtin_amdgcn_s_setprio(0);
                // ---- silu + mask in-place: j = j0 + (r&3)+8(r>>2)+4h5 ----
#pragma unroll
                for (int r = 0; r < 16; ++r) {
                    const int gj = j0 + (r & 3) + ((r >> 2) << 3) + (h5 << 2);
                    const float s = sacc[r];
                    const float e2 = __builtin_amdgcn_exp2f(-(s * C2));
                    const float p = s * C1 * __builtin_amdgcn_rcpf(1.f + e2);
                    const bool valid = (gj < L) && ((gj <= qrow) || (qrow >= cap));
                    sacc[r] = valid ? p : 0.f;
                }
                // ---- pack + permlane exchange -> PV A-frags; PV MFMA ----
#pragma unroll
                for (int sg = 0; sg < 2; ++sg) {
                    unsigned int a  = cvt_pk_bf16(sacc[sg * 8 + 0], sacc[sg * 8 + 1]);
                    unsigned int bb = cvt_pk_bf16(sacc[sg * 8 + 2], sacc[sg * 8 + 3]);
                    unsigned int cc = cvt_pk_bf16(sacc[sg * 8 + 4], sacc[sg * 8 + 5]);
                    unsigned int dd = cvt_pk_bf16(sacc[sg * 8 + 6], sacc[sg * 8 + 7]);
                    asm volatile("v_permlane32_swap_b32 %0, %1" : "+v"(a), "+v"(cc));
                    asm volatile("v_permlane32_swap_b32 %0, %1" : "+v"(bb), "+v"(dd));
                    PA8 pa;
                    pa.u[0] = a; pa.u[1] = bb; pa.u[2] = cc; pa.u[3] = dd;
                    __builtin_amdgcn_s_setprio(1);
#pragma unroll
                    for (int dt = 0; dt < 4; ++dt) {
                        bf16x8 vb = *(const bf16x8*)(bV + (sg * 2 + h5) * 2048 +
                                                     (dt * 32 + l31) * 16);
                        oacc[dt] = __builtin_amdgcn_mfma_f32_32x32x16_bf16(pa.v, vb, oacc[dt], 0, 0, 0);
                    }
                    __builtin_amdgcn_s_setprio(0);
                }
            }

            if (c + 1 < nch) write_buf((c + 1) & 1);
            if (c + 2 < nch) load_chunk((c + 2) << 5);
            // lgkm-only barrier: global prefetch stays in flight
            asm volatile("s_waitcnt lgkmcnt(0)\n\ts_barrier" ::: "memory");
        }

        // ---- write O (f32): row = wr0+(r&3)+8(r>>2)+4h5, col = dt*32+l31 ----
#pragma unroll
        for (int r = 0; r < 16; ++r) {
            const int gir = wr0 + (r & 3) + ((r >> 2) << 3) + (h5 << 2);
            if (gir < L) {
                float* op = Out + (size_t)(s0 + gir) * HD + h * 128 + l31;
                op[0]  = oacc[0][r];
                op[32] = oacc[1][r];
                op[64] = oacc[2][r];
                op[96] = oacc[3][r];
            }
        }
    }
}

extern "C" void kernel_launch(void* const* d_in, const int* in_sizes, int n_in,
                              void* d_out, int out_size, void* d_ws, size_t ws_size,
                              hipStream_t stream) {
    (void)in_sizes; (void)n_in; (void)ws_size; (void)out_size;
    const float* q = (const float*)d_in[0];
    const float* k = (const float*)d_in[1];
    const float* v = (const float*)d_in[2];
    const int* offs = (const int*)d_in[3];
    const int* ntgt = (const int*)d_in[4];
    float* out = (float*)d_out;
    unsigned int* ctr = (unsigned int*)d_ws;
    hipMemsetAsync(ctr, 0, 4, stream);
    dim3 grid(1024, 1, 1), block(256, 1, 1);
    hipLaunchKernelGGL(hstu_attn_fwd, grid, block, 0, stream, q, k, v, offs, ntgt, out, ctr);
}